// Round 6
// baseline (201.035 us; speedup 1.0000x reference)
//
#include <hip/hip_runtime.h>

// Erosion = 18x18 separable min-filter, SAME padding (lo=8, hi=9) with +inf,
// applied to x*0.5+0.5. Affine is monotone & exact: min-filter raw x, apply
// *0.5+0.5 once at the end (bitwise identical).
//
// R6: remove the phase-1 tail + max occupancy.
//  Diagnosis R1-R5: every variant had units%256!=0 -> ~40 threads ran TWO
//  full load-units while 216 idled at the barrier; during that tail the CU's
//  in-flight bytes collapse -> latency-bound ~3 TB/s regardless of structure.
//  Fix: tile 128x32 -> phase 1 = 37 f4cols x 4 segs = 148 units, exactly one
//  per thread (zero tail); accumulator van Herk keeps VGPR<=64 so
//  __launch_bounds__(256,8) + LDS 19.5KB give 8 blocks/CU = 32 waves (max).
//  Phase 2 = 1024 units = exactly 4/thread; nontemporal f4 stores.

#define IMG 512

typedef float f32x4 __attribute__((ext_vector_type(4)));

__device__ __forceinline__ float4 f4min(float4 a, float4 b) {
    return make_float4(fminf(a.x, b.x), fminf(a.y, b.y),
                       fminf(a.z, b.z), fminf(a.w, b.w));
}

__global__ __launch_bounds__(256, 8)
void erode_fused_22187801051678(const float* __restrict__ in,
                                float* __restrict__ out) {
    __shared__ float4 B4[32][38];  // [row][f4col]; 37 used, +1 pad

    const int tid = threadIdx.x;
    const int w0 = blockIdx.x * 128;
    const int h0 = blockIdx.y * 32;
    const size_t plane = (size_t)blockIdx.z * (size_t)(IMG * IMG);

    const float4 VINF = make_float4(__builtin_inff(), __builtin_inff(),
                                    __builtin_inff(), __builtin_inff());

    // ---- phase 1: vertical 18-tap min. 148 units = 37 f4cols x 4 segs,
    // exactly one unit per thread (tid 148..255 idle -> no load tail).
    if (tid < 148) {
        const int c = tid % 37;
        const int s = tid / 37;
        const int cb = w0 - 8 + 4 * c;                  // 4-aligned col base
        const bool wok = (unsigned)cb < (unsigned)IMG;  // whole f4 in or out
        const int cbc = min(max(cb, 0), IMG - 4);       // clamped valid base
        const int rbase = h0 + 8 * s - 8;               // input row of x[0]
        const float* bp = in + plane + cbc;

        float4 acc[8];
#pragma unroll
        for (int j = 0; j < 8; ++j) acc[j] = VINF;

        // out[j] = min over input rows i in [j, j+17]; accumulate per row.
        // Loads are independent of the acc chains -> scheduler overlaps them.
#pragma unroll
        for (int i = 0; i < 25; ++i) {
            const int gh = rbase + i;
            const int ghc = min(max(gh, 0), IMG - 1);
            float4 x = *reinterpret_cast<const float4*>(bp + (size_t)ghc * IMG);
            if (!(wok && (unsigned)gh < (unsigned)IMG)) x = VINF;
#pragma unroll
            for (int j = 0; j < 8; ++j)
                if (j <= i && i <= j + 17)      // folds statically per (i,j)
                    acc[j] = f4min(acc[j], x);
        }
        const int rb = 8 * s;
#pragma unroll
        for (int j = 0; j < 8; ++j) B4[rb + j][c] = acc[j];
    }
    __syncthreads();

    // ---- phase 2: horizontal 18-tap min + affine + nontemporal f4 stores.
    // 1024 units = 32 rows x 32 f4-outcols = exactly 4 sweeps of 256.
    const int gq = tid & 31;
    const int r0 = tid >> 5;
#pragma unroll
    for (int sw = 0; sw < 4; ++sw) {
        const int r = r0 + 8 * sw;
        float z[24];
#pragma unroll
        for (int k = 0; k < 6; ++k) {
            const float4 v = B4[r][gq + k];
            z[4 * k + 0] = v.x; z[4 * k + 1] = v.y;
            z[4 * k + 2] = v.z; z[4 * k + 3] = v.w;
        }
        // o[t] = min(z[t..t+17]); shared core = min(z[3..17])
        const float a0 = fminf(z[3], z[4]);
        const float a1 = fminf(z[5], z[6]);
        const float a2 = fminf(z[7], z[8]);
        const float a3 = fminf(z[9], z[10]);
        const float a4 = fminf(z[11], z[12]);
        const float a5 = fminf(z[13], z[14]);
        const float a6 = fminf(z[15], z[16]);
        const float b0 = fminf(a0, a1), b1 = fminf(a2, a3);
        const float b2 = fminf(a4, a5), b3 = fminf(a6, z[17]);
        const float core = fminf(fminf(b0, b1), fminf(b2, b3));
        const float o0 = fminf(fminf(z[0], z[1]), fminf(z[2], core));
        const float o1 = fminf(fminf(z[1], z[2]), fminf(core, z[18]));
        const float o2 = fminf(fminf(z[2], core), fminf(z[18], z[19]));
        const float o3 = fminf(fminf(core, z[18]), fminf(z[19], z[20]));
        f32x4 res = {o0 * 0.5f + 0.5f, o1 * 0.5f + 0.5f,
                     o2 * 0.5f + 0.5f, o3 * 0.5f + 0.5f};
        __builtin_nontemporal_store(
            res, reinterpret_cast<f32x4*>(
                     out + plane + (size_t)(h0 + r) * IMG + (w0 + 4 * gq)));
    }
}

extern "C" void kernel_launch(void* const* d_in, const int* in_sizes, int n_in,
                              void* d_out, int out_size, void* d_ws, size_t ws_size,
                              hipStream_t stream) {
    const float* x = (const float*)d_in[0];
    float* out = (float*)d_out;
    const int planes = in_sizes[0] / (IMG * IMG);  // 96 for (32,3,512,512)
    dim3 grid(IMG / 128, IMG / 32, planes);
    erode_fused_22187801051678<<<grid, dim3(256), 0, stream>>>(x, out);
}